// Round 6
// baseline (1916.158 us; speedup 1.0000x reference)
//
#include <hip/hip_runtime.h>
#include <hip/hip_bf16.h>
#include <stdint.h>

#define BATCH 32
#define LENC  49
#define TSTEPS 24
#define HID   1024
#define VOCAB 32000
#define KSTEP 2048   // per-step x width: context | h
#define NG    4096   // 4*HID gates
#define KCHUNK 8     // split-K partial slots (kc*2 + wk)
#define NBLK  256    // persistent grid; 2 blocks/CU capacity -> co-residency guaranteed

typedef __bf16 bf16_t;
typedef short  s16x8 __attribute__((ext_vector_type(8)));   // bf16x8 bit-pattern (MFMA frag)
typedef float  f32x4 __attribute__((ext_vector_type(4)));

__device__ __forceinline__ float warp_sum(float v){
#pragma unroll
  for (int o = 32; o > 0; o >>= 1) v += __shfl_down(v, o, 64);
  return v;
}
__device__ __forceinline__ float warp_max(float v){
#pragma unroll
  for (int o = 32; o > 0; o >>= 1) v = fmaxf(v, __shfl_down(v, o, 64));
  return v;
}

__device__ __forceinline__ short bf16bits(float f){
  union { bf16_t h; short s; } u; u.h = (bf16_t)f; return u.s;
}
__device__ __forceinline__ float bits2f(short s){
  union { uint32_t u; float f; } b; b.u = ((uint32_t)(uint16_t)s) << 16; return b.f;
}
// split f into hi + lo (bf16 each); f = hi + lo + O(2^-18 |f|)
__device__ __forceinline__ void split1(float f, short& hi, short& lo){
  hi = bf16bits(f);
  lo = bf16bits(f - bits2f(hi));
}
__device__ __forceinline__ void split4(float4 f, short4& hi, short4& lo){
  split1(f.x, hi.x, lo.x); split1(f.y, hi.y, lo.y);
  split1(f.z, hi.z, lo.z); split1(f.w, hi.w, lo.w);
}
__device__ __forceinline__ short4 pack4(float4 f){
  short4 o; o.x = bf16bits(f.x); o.y = bf16bits(f.y); o.z = bf16bits(f.z); o.w = bf16bits(f.w);
  return o;
}
__device__ __forceinline__ s16x8 load8(const bf16_t* p){ return *(const s16x8*)p; }
__device__ __forceinline__ s16x8 load8(const float* p){
  float4 f0 = *(const float4*)p;
  float4 f1 = *(const float4*)(p + 4);
  s16x8 r;
  r[0]=bf16bits(f0.x); r[1]=bf16bits(f0.y); r[2]=bf16bits(f0.z); r[3]=bf16bits(f0.w);
  r[4]=bf16bits(f1.x); r[5]=bf16bits(f1.y); r[6]=bf16bits(f1.z); r[7]=bf16bits(f1.w);
  return r;
}
__device__ __forceinline__ void load8split(const float* p, s16x8& hi, s16x8& lo){
  float4 f0 = *(const float4*)p;
  float4 f1 = *(const float4*)(p + 4);
  short h, l;
  split1(f0.x, h, l); hi[0]=h; lo[0]=l;  split1(f0.y, h, l); hi[1]=h; lo[1]=l;
  split1(f0.z, h, l); hi[2]=h; lo[2]=l;  split1(f0.w, h, l); hi[3]=h; lo[3]=l;
  split1(f1.x, h, l); hi[4]=h; lo[4]=l;  split1(f1.y, h, l); hi[5]=h; lo[5]=l;
  split1(f1.z, h, l); hi[6]=h; lo[6]=l;  split1(f1.w, h, l); hi[7]=h; lo[7]=l;
}
// one LSTM element: returns c_new, sets hn
__device__ __forceinline__ float cell1(float gi, float gf, float gg, float go, float co, float& hn){
  float si = 1.f / (1.f + expf(-gi));
  float sf = 1.f / (1.f + expf(-gf));
  float so = 1.f / (1.f + expf(-go));
  float cn = sf * co + si * tanhf(gg);
  hn = so * tanhf(cn);
  return cn;
}

// ---- grid barrier (device-scope). Co-residency guaranteed: 256 blocks, 2/CU capacity. ----
__device__ __forceinline__ void gbar(int* bar, int target){
  __syncthreads();
  if (threadIdx.x == 0){
    __builtin_amdgcn_fence(__ATOMIC_RELEASE, "agent");   // flush this block's writes (per-XCD L2 wb)
    int old = __hip_atomic_fetch_add(&bar[0], 1, __ATOMIC_ACQ_REL, __HIP_MEMORY_SCOPE_AGENT);
    if (old == NBLK - 1){
      __hip_atomic_store(&bar[0], 0, __ATOMIC_RELAXED, __HIP_MEMORY_SCOPE_AGENT);
      __hip_atomic_fetch_add(&bar[1], 1, __ATOMIC_RELEASE, __HIP_MEMORY_SCOPE_AGENT);
    } else {
      while (__hip_atomic_load(&bar[1], __ATOMIC_RELAXED, __HIP_MEMORY_SCOPE_AGENT) < target){
        __builtin_amdgcn_s_sleep(1);
      }
    }
    __builtin_amdgcn_fence(__ATOMIC_ACQUIRE, "agent");   // invalidate stale lines
  }
  __syncthreads();
}

// ---- barrier state init (runs every launch/replay) ----
__global__ void k_binit(int* __restrict__ bar){
  if (threadIdx.x < 16) bar[threadIdx.x] = 0;
}

// ---- fp32 -> bf16 bulk convert (n4 = element count / 4) ----
__global__ void k_cvt(const float* __restrict__ src, bf16_t* __restrict__ dst, int n4){
  int i = blockIdx.x * 256 + threadIdx.x;
  if (i < n4){
    float4 f = ((const float4*)src)[i];
    ((short4*)dst)[i] = pack4(f);
  }
}

// ---- one-time: gemb[t][b][n] = emb(t,b) . W_ih[:,1024:2048]^T + b_ih[n] + b_hh[n] ----
__global__ __launch_bounds__(256) void k_gemb(const int* __restrict__ caps,
                                              const float* __restrict__ table,
                                              const float* __restrict__ wih,
                                              const float* __restrict__ bih,
                                              const float* __restrict__ bhh,
                                              float* __restrict__ gemb){
  int tid = threadIdx.x;
  int wave = tid >> 6, lane = tid & 63;
  int quad = lane >> 4, r16 = lane & 15;
  int nwb = blockIdx.x * 128 + wave * 32;
  int t = blockIdx.y;                           // one timestep per m-block (m = t*32 + b)
  const float* rowA = table + (size_t)caps[(size_t)r16 * TSTEPS + t] * HID;
  const float* rowB = table + (size_t)caps[(size_t)(r16 + 16) * TSTEPS + t] * HID;
  f32x4 acc[2][2] = {};

  for (int kk = 0; kk < 32; ++kk){
    int ko = kk * 32 + quad * 8;
    s16x8 a0h, a0l, a1h, a1l, b0h, b0l, b1h, b1l;
    load8split(rowA + ko, a0h, a0l);
    load8split(rowB + ko, a1h, a1l);
    load8split(wih + (size_t)(nwb + r16)      * 2048 + 1024 + ko, b0h, b0l);
    load8split(wih + (size_t)(nwb + 16 + r16) * 2048 + 1024 + ko, b1h, b1l);
    acc[0][0] = __builtin_amdgcn_mfma_f32_16x16x32_bf16(a0h, b0h, acc[0][0], 0, 0, 0);
    acc[0][0] = __builtin_amdgcn_mfma_f32_16x16x32_bf16(a0h, b0l, acc[0][0], 0, 0, 0);
    acc[0][0] = __builtin_amdgcn_mfma_f32_16x16x32_bf16(a0l, b0h, acc[0][0], 0, 0, 0);
    acc[1][0] = __builtin_amdgcn_mfma_f32_16x16x32_bf16(a1h, b0h, acc[1][0], 0, 0, 0);
    acc[1][0] = __builtin_amdgcn_mfma_f32_16x16x32_bf16(a1h, b0l, acc[1][0], 0, 0, 0);
    acc[1][0] = __builtin_amdgcn_mfma_f32_16x16x32_bf16(a1l, b0h, acc[1][0], 0, 0, 0);
    acc[0][1] = __builtin_amdgcn_mfma_f32_16x16x32_bf16(a0h, b1h, acc[0][1], 0, 0, 0);
    acc[0][1] = __builtin_amdgcn_mfma_f32_16x16x32_bf16(a0h, b1l, acc[0][1], 0, 0, 0);
    acc[0][1] = __builtin_amdgcn_mfma_f32_16x16x32_bf16(a0l, b1h, acc[0][1], 0, 0, 0);
    acc[1][1] = __builtin_amdgcn_mfma_f32_16x16x32_bf16(a1h, b1h, acc[1][1], 0, 0, 0);
    acc[1][1] = __builtin_amdgcn_mfma_f32_16x16x32_bf16(a1h, b1l, acc[1][1], 0, 0, 0);
    acc[1][1] = __builtin_amdgcn_mfma_f32_16x16x32_bf16(a1l, b1h, acc[1][1], 0, 0, 0);
  }
#pragma unroll
  for (int mt = 0; mt < 2; ++mt)
#pragma unroll
    for (int nt = 0; nt < 2; ++nt)
#pragma unroll
      for (int r = 0; r < 4; ++r){
        int m = mt * 16 + quad * 4 + r;          // b index
        int n = nwb + nt * 16 + r16;
        gemb[((size_t)t * BATCH + m) * NG + n] = acc[mt][nt][r] + bih[n] + bhh[n];
      }
}

// ---- persistent loop kernel: 256 blocks, weights REGISTER-resident ----
// Block bid owns rows [nwb,nwb+64) x cols [kb,kb+512) of [W_ih_ctx | W_hh].
// Each thread's fixed fragment set (2 rows x 8 k-groups x hi/lo = 256 shorts)
// is staged ONCE into 128 VGPRs; the K-loop reads only x from L2.
// Per step: blocks 0..31: cell(t-1)+attention+x-write; gbar; all: gates GEMM; gbar.
__global__ __launch_bounds__(256, 1) void k_loop(const float* __restrict__ feat,
                                                 const float* __restrict__ gemb,
                                                 const float* __restrict__ wih,
                                                 const float* __restrict__ whh,
                                                 float* __restrict__ gbuf,
                                                 bf16_t* __restrict__ hall,
                                                 bf16_t* __restrict__ xh,
                                                 bf16_t* __restrict__ xl,
                                                 int* __restrict__ bar){
  __shared__ float sh[HID];            // h (blocks 0..31 only)
  __shared__ float sw[64];             // softmax weights

  const int bid  = blockIdx.x;
  const int tid  = threadIdx.x;
  const int nwb  = (bid >> 2) * 64;    // n-tile base (64 gate rows)
  const int kc   = bid & 3;            // k-chunk (512 cols)
  const int kb   = kc * 512;

  const int wave = tid >> 6, lane = tid & 63;
  const int quad = lane >> 4, r16 = lane & 15;
  const int wn = wave & 1, wk = wave >> 1;

  // ---- one-time: stage weight fragments into registers (hi/lo split) ----
  s16x8 wb0h[8], wb0l[8], wb1h[8], wb1l[8];
  {
    const int rr0 = nwb + wn * 32 + r16;
    const int rr1 = rr0 + 16;
#pragma unroll
    for (int kk = 0; kk < 8; ++kk){
      int kg = kb + wk * 256 + kk * 32 + quad * 8;
      const float* p0 = (kg < 1024) ? (wih + (size_t)rr0 * 2048 + kg)
                                    : (whh + (size_t)rr0 * 1024 + (kg - 1024));
      const float* p1 = (kg < 1024) ? (wih + (size_t)rr1 * 2048 + kg)
                                    : (whh + (size_t)rr1 * 1024 + (kg - 1024));
      load8split(p0, wb0h[kk], wb0l[kk]);
      load8split(p1, wb1h[kk], wb1l[kk]);
    }
  }

  float4 c_reg = make_float4(0.f, 0.f, 0.f, 0.f);   // blocks 0..31: cell state
  int gen = 0;

  for (int t = 0; t < TSTEPS; ++t){
    // ================= phase A: cell + attention (blocks 0..31) =================
    if (bid < BATCH){
      if (t == 0){
        ((float4*)sh)[tid] = make_float4(0.f, 0.f, 0.f, 0.f);
      } else {
        const float* ge = gemb + ((size_t)(t - 1) * BATCH + bid) * NG;
        float4 gi = ((const float4*)(ge       ))[tid];
        float4 gf = ((const float4*)(ge + 1024))[tid];
        float4 gg = ((const float4*)(ge + 2048))[tid];
        float4 go = ((const float4*)(ge + 3072))[tid];
#pragma unroll
        for (int c = 0; c < KCHUNK; ++c){
          const float* g = gbuf + ((size_t)c * BATCH + bid) * NG;
          float4 a;
          a = ((const float4*)(g       ))[tid]; gi.x+=a.x; gi.y+=a.y; gi.z+=a.z; gi.w+=a.w;
          a = ((const float4*)(g + 1024))[tid]; gf.x+=a.x; gf.y+=a.y; gf.z+=a.z; gf.w+=a.w;
          a = ((const float4*)(g + 2048))[tid]; gg.x+=a.x; gg.y+=a.y; gg.z+=a.z; gg.w+=a.w;
          a = ((const float4*)(g + 3072))[tid]; go.x+=a.x; go.y+=a.y; go.z+=a.z; go.w+=a.w;
        }
        float4 hn, cn;
        cn.x = cell1(gi.x, gf.x, gg.x, go.x, c_reg.x, hn.x);
        cn.y = cell1(gi.y, gf.y, gg.y, go.y, c_reg.y, hn.y);
        cn.z = cell1(gi.z, gf.z, gg.z, go.z, c_reg.z, hn.z);
        cn.w = cell1(gi.w, gf.w, gg.w, go.w, c_reg.w, hn.w);
        c_reg = cn;
        ((float4*)sh)[tid] = hn;
        ((short4*)(hall + ((size_t)(t - 1) * BATCH + bid) * HID))[tid] = pack4(hn);
      }
      __syncthreads();

      const float4* fb4 = (const float4*)(feat + (size_t)bid * LENC * HID);
      const float4* sh4 = (const float4*)sh;
      for (int l = wave; l < LENC; l += 4){
        float acc = 0.f;
        for (int k4 = lane; k4 < 256; k4 += 64){
          float4 f = fb4[l * 256 + k4];
          float4 h = sh4[k4];
          acc = fmaf(f.x, h.x, acc); acc = fmaf(f.y, h.y, acc);
          acc = fmaf(f.z, h.z, acc); acc = fmaf(f.w, h.w, acc);
        }
        acc = warp_sum(acc);
        if (lane == 0) sw[l] = acc;
      }
      __syncthreads();
      if (tid < 64){
        float s = (tid < LENC) ? sw[tid] : -1e30f;
        float m = warp_max(s);
        m = __shfl(m, 0, 64);
        float e = (tid < LENC) ? expf(s - m) : 0.f;
        float ssum = warp_sum(e);
        ssum = __shfl(ssum, 0, 64);
        if (tid < LENC) sw[tid] = e / ssum;
      }
      __syncthreads();
      // context -> x[b][0:1024] (split)
      {
        float4 a = make_float4(0.f, 0.f, 0.f, 0.f);
#pragma unroll 7
        for (int l = 0; l < LENC; ++l){
          float wl = sw[l];
          float4 f = fb4[l * 256 + tid];
          a.x = fmaf(wl, f.x, a.x); a.y = fmaf(wl, f.y, a.y);
          a.z = fmaf(wl, f.z, a.z); a.w = fmaf(wl, f.w, a.w);
        }
        short4 h4, l4;
        split4(a, h4, l4);
        ((short4*)(xh + (size_t)bid * KSTEP))[tid] = h4;
        ((short4*)(xl + (size_t)bid * KSTEP))[tid] = l4;
      }
      // h -> x[b][1024:2048] (split)
      {
        float4 f = ((const float4*)sh)[tid];
        short4 h4, l4;
        split4(f, h4, l4);
        ((short4*)(xh + (size_t)bid * KSTEP + 1024))[tid] = h4;
        ((short4*)(xl + (size_t)bid * KSTEP + 1024))[tid] = l4;
      }
    }
    ++gen; gbar(bar, gen);              // x ready everywhere

    // ================= phase B: gates GEMM, weights in registers =================
    {
      f32x4 acc[2][2] = {};
#pragma unroll
      for (int kk = 0; kk < 8; ++kk){
        int kg = kb + wk * 256 + kk * 32 + quad * 8;
        s16x8 a0h = load8(xh + (size_t)r16        * KSTEP + kg);
        s16x8 a0l = load8(xl + (size_t)r16        * KSTEP + kg);
        s16x8 a1h = load8(xh + (size_t)(r16 + 16) * KSTEP + kg);
        s16x8 a1l = load8(xl + (size_t)(r16 + 16) * KSTEP + kg);
        // hi*hi + hi*lo + lo*hi (lo*lo dropped: 2^-18)
        acc[0][0] = __builtin_amdgcn_mfma_f32_16x16x32_bf16(a0h, wb0h[kk], acc[0][0], 0, 0, 0);
        acc[0][0] = __builtin_amdgcn_mfma_f32_16x16x32_bf16(a0h, wb0l[kk], acc[0][0], 0, 0, 0);
        acc[0][0] = __builtin_amdgcn_mfma_f32_16x16x32_bf16(a0l, wb0h[kk], acc[0][0], 0, 0, 0);
        acc[1][0] = __builtin_amdgcn_mfma_f32_16x16x32_bf16(a1h, wb0h[kk], acc[1][0], 0, 0, 0);
        acc[1][0] = __builtin_amdgcn_mfma_f32_16x16x32_bf16(a1h, wb0l[kk], acc[1][0], 0, 0, 0);
        acc[1][0] = __builtin_amdgcn_mfma_f32_16x16x32_bf16(a1l, wb0h[kk], acc[1][0], 0, 0, 0);
        acc[0][1] = __builtin_amdgcn_mfma_f32_16x16x32_bf16(a0h, wb1h[kk], acc[0][1], 0, 0, 0);
        acc[0][1] = __builtin_amdgcn_mfma_f32_16x16x32_bf16(a0h, wb1l[kk], acc[0][1], 0, 0, 0);
        acc[0][1] = __builtin_amdgcn_mfma_f32_16x16x32_bf16(a0l, wb1h[kk], acc[0][1], 0, 0, 0);
        acc[1][1] = __builtin_amdgcn_mfma_f32_16x16x32_bf16(a1h, wb1h[kk], acc[1][1], 0, 0, 0);
        acc[1][1] = __builtin_amdgcn_mfma_f32_16x16x32_bf16(a1h, wb1l[kk], acc[1][1], 0, 0, 0);
        acc[1][1] = __builtin_amdgcn_mfma_f32_16x16x32_bf16(a1l, wb1h[kk], acc[1][1], 0, 0, 0);
      }
      int kslot = kc * 2 + wk;                   // 0..7
#pragma unroll
      for (int mt = 0; mt < 2; ++mt)
#pragma unroll
        for (int nt = 0; nt < 2; ++nt)
#pragma unroll
          for (int r = 0; r < 4; ++r){
            int m = mt * 16 + quad * 4 + r;      // batch index
            int n = nwb + wn * 32 + nt * 16 + r16;
            gbuf[((size_t)kslot * BATCH + m) * NG + n] = acc[mt][nt][r];
          }
    }
    ++gen; gbar(bar, gen);              // gbuf ready for next step's cell
  }

  // ---- tail: final cell -> hall[TSTEPS-1] ----
  if (bid < BATCH){
    const float* ge = gemb + ((size_t)(TSTEPS - 1) * BATCH + bid) * NG;
    float4 gi = ((const float4*)(ge       ))[tid];
    float4 gf = ((const float4*)(ge + 1024))[tid];
    float4 gg = ((const float4*)(ge + 2048))[tid];
    float4 go = ((const float4*)(ge + 3072))[tid];
#pragma unroll
    for (int c = 0; c < KCHUNK; ++c){
      const float* g = gbuf + ((size_t)c * BATCH + bid) * NG;
      float4 a;
      a = ((const float4*)(g       ))[tid]; gi.x+=a.x; gi.y+=a.y; gi.z+=a.z; gi.w+=a.w;
      a = ((const float4*)(g + 1024))[tid]; gf.x+=a.x; gf.y+=a.y; gf.z+=a.z; gf.w+=a.w;
      a = ((const float4*)(g + 2048))[tid]; gg.x+=a.x; gg.y+=a.y; gg.z+=a.z; gg.w+=a.w;
      a = ((const float4*)(g + 3072))[tid]; go.x+=a.x; go.y+=a.y; go.z+=a.z; go.w+=a.w;
    }
    float4 hn;
    cell1(gi.x, gf.x, gg.x, go.x, c_reg.x, hn.x);
    cell1(gi.y, gf.y, gg.y, go.y, c_reg.y, hn.y);
    cell1(gi.z, gf.z, gg.z, go.z, c_reg.z, hn.z);
    cell1(gi.w, gf.w, gg.w, go.w, c_reg.w, hn.w);
    ((short4*)(hall + ((size_t)(TSTEPS - 1) * BATCH + bid) * HID))[tid] = pack4(hn);
  }
}

// ---- batched logits GEMM: [768 x 1024] x [1024 x 32000]^T + b_out (fp32 out) ----
template <typename WT>
__global__ __launch_bounds__(256) void k_logits(const bf16_t* __restrict__ hall,
                                                const WT* __restrict__ wout,
                                                const float* __restrict__ bout,
                                                float* __restrict__ out){
  int mh = blockIdx.x * 384;
  int n0 = blockIdx.y * 128;
  int tid = threadIdx.x;
  int wave = tid >> 6, lane = tid & 63;
  int wm = wave >> 1, wn = wave & 1;
  int quad = lane >> 4, r16 = lane & 15;

  for (int mc = 0; mc < 3; ++mc){
    int m0 = mh + mc * 128;
    f32x4 acc[4][4] = {};
#pragma unroll 2
    for (int kk = 0; kk < 32; ++kk){
      int k0 = kk * 32 + quad * 8;
      s16x8 af[4], bfr[4];
#pragma unroll
      for (int mt = 0; mt < 4; ++mt){
        int m = m0 + wm * 64 + mt * 16 + r16;
        af[mt] = load8(hall + (size_t)m * HID + k0);
      }
#pragma unroll
      for (int nt = 0; nt < 4; ++nt){
        int n = n0 + wn * 64 + nt * 16 + r16;
        bfr[nt] = load8(wout + (size_t)n * HID + k0);
      }
#pragma unroll
      for (int mt = 0; mt < 4; ++mt)
#pragma unroll
        for (int nt = 0; nt < 4; ++nt)
          acc[mt][nt] = __builtin_amdgcn_mfma_f32_16x16x32_bf16(af[mt], bfr[nt], acc[mt][nt], 0, 0, 0);
    }

#pragma unroll
    for (int mt = 0; mt < 4; ++mt){
      int mbase = m0 + wm * 64 + mt * 16 + quad * 4;
#pragma unroll
      for (int r = 0; r < 4; ++r){
        int m = mbase + r;
        int tt = m >> 5, b = m & 31;            // hall row m = t*32 + b
        size_t outrow = ((size_t)b * TSTEPS + tt) * VOCAB;
#pragma unroll
        for (int nt = 0; nt < 4; ++nt){
          int n = n0 + wn * 64 + nt * 16 + r16;
          out[outrow + n] = acc[mt][nt][r] + bout[n];
        }
      }
    }
  }
}

extern "C" void kernel_launch(void* const* d_in, const int* in_sizes, int n_in,
                              void* d_out, int out_size, void* d_ws, size_t ws_size,
                              hipStream_t stream) {
  const float* feat  = (const float*)d_in[0];
  const int*   caps  = (const int*)d_in[1];
  const float* table = (const float*)d_in[2];
  const float* wih   = (const float*)d_in[3];
  const float* whh   = (const float*)d_in[4];
  const float* bih   = (const float*)d_in[5];
  const float* bhh   = (const float*)d_in[6];
  const float* wout  = (const float*)d_in[7];
  const float* bout  = (const float*)d_in[8];
  float* out = (float*)d_out;
  (void)in_sizes; (void)n_in; (void)out_size;

  char* ws = (char*)d_ws;
  bf16_t* hall  = (bf16_t*)(ws);                 //  1,572,864 ->  1,572,864
  bf16_t* xh    = (bf16_t*)(ws + 1572864);       //    131,072 ->  1,703,936
  bf16_t* xl    = (bf16_t*)(ws + 1703936);       //    131,072 ->  1,835,008
  float*  gbuf  = (float*)(ws + 1835008);        //  4,194,304 ->  6,029,312  (8 split-K partials)
  float*  gemb  = (float*)(ws + 6029312);        // 12,582,912 -> 18,612,224  (emb gates + biases)
  int*    bar   = (int*)  (ws + 18612224);       //         64 -> 18,612,288  (grid barrier)
  bf16_t* woutb = (bf16_t*)(ws + 18612288);      // 65,536,000 -> 84,148,288

  const bool useWout = (ws_size >= (size_t)84148288);

  k_binit<<<dim3(1), dim3(64), 0, stream>>>(bar);
  // one-time: embedding contribution to gates for all timesteps (+ biases folded in)
  k_gemb<<<dim3(32, TSTEPS), dim3(256), 0, stream>>>(caps, table, wih, bih, bhh, gemb);
  // persistent 24-step loop (weights register-resident; 2 grid barriers/step)
  k_loop<<<dim3(NBLK), dim3(256), 0, stream>>>(feat, gemb, wih, whh, gbuf, hall, xh, xl, bar);

  if (useWout){
    k_cvt<<<dim3(32000), dim3(256), 0, stream>>>(wout, woutb, VOCAB * HID / 4);
    k_logits<bf16_t><<<dim3(2, VOCAB / 128), dim3(256), 0, stream>>>(hall, woutb, bout, out);
  } else {
    k_logits<float><<<dim3(2, VOCAB / 128), dim3(256), 0, stream>>>(hall, wout, bout, out);
  }
}

// Round 8
// 1751.174 us; speedup vs baseline: 1.0942x; 1.0942x over previous
//
#include <hip/hip_runtime.h>
#include <hip/hip_bf16.h>
#include <stdint.h>

#define BATCH 32
#define LENC  49
#define TSTEPS 24
#define HID   1024
#define VOCAB 32000
#define KSTEP 2048   // per-step x width: context | h
#define NG    4096   // 4*HID gates
#define KCHUNK 8     // split-K partial slots (kc*2 + wk)
#define NBLK  256    // persistent grid; 2 blocks/CU capacity -> co-residency guaranteed

typedef __bf16 bf16_t;
typedef short  s16x8 __attribute__((ext_vector_type(8)));   // bf16x8 bit-pattern (MFMA frag)
typedef float  f32x4 __attribute__((ext_vector_type(4)));

__device__ __forceinline__ float warp_sum(float v){
#pragma unroll
  for (int o = 32; o > 0; o >>= 1) v += __shfl_down(v, o, 64);
  return v;
}
__device__ __forceinline__ float warp_max(float v){
#pragma unroll
  for (int o = 32; o > 0; o >>= 1) v = fmaxf(v, __shfl_down(v, o, 64));
  return v;
}

__device__ __forceinline__ short bf16bits(float f){
  union { bf16_t h; short s; } u; u.h = (bf16_t)f; return u.s;
}
__device__ __forceinline__ float bits2f(short s){
  union { uint32_t u; float f; } b; b.u = ((uint32_t)(uint16_t)s) << 16; return b.f;
}
// split f into hi + lo (bf16 each); f = hi + lo + O(2^-18 |f|)
__device__ __forceinline__ void split1(float f, short& hi, short& lo){
  hi = bf16bits(f);
  lo = bf16bits(f - bits2f(hi));
}
__device__ __forceinline__ void split4(float4 f, short4& hi, short4& lo){
  split1(f.x, hi.x, lo.x); split1(f.y, hi.y, lo.y);
  split1(f.z, hi.z, lo.z); split1(f.w, hi.w, lo.w);
}
__device__ __forceinline__ short4 pack4(float4 f){
  short4 o; o.x = bf16bits(f.x); o.y = bf16bits(f.y); o.z = bf16bits(f.z); o.w = bf16bits(f.w);
  return o;
}
__device__ __forceinline__ s16x8 load8(const bf16_t* p){ return *(const s16x8*)p; }
__device__ __forceinline__ s16x8 load8(const float* p){
  float4 f0 = *(const float4*)p;
  float4 f1 = *(const float4*)(p + 4);
  s16x8 r;
  r[0]=bf16bits(f0.x); r[1]=bf16bits(f0.y); r[2]=bf16bits(f0.z); r[3]=bf16bits(f0.w);
  r[4]=bf16bits(f1.x); r[5]=bf16bits(f1.y); r[6]=bf16bits(f1.z); r[7]=bf16bits(f1.w);
  return r;
}
__device__ __forceinline__ void load8split(const float* p, s16x8& hi, s16x8& lo){
  float4 f0 = *(const float4*)p;
  float4 f1 = *(const float4*)(p + 4);
  short h, l;
  split1(f0.x, h, l); hi[0]=h; lo[0]=l;  split1(f0.y, h, l); hi[1]=h; lo[1]=l;
  split1(f0.z, h, l); hi[2]=h; lo[2]=l;  split1(f0.w, h, l); hi[3]=h; lo[3]=l;
  split1(f1.x, h, l); hi[4]=h; lo[4]=l;  split1(f1.y, h, l); hi[5]=h; lo[5]=l;
  split1(f1.z, h, l); hi[6]=h; lo[6]=l;  split1(f1.w, h, l); hi[7]=h; lo[7]=l;
}
// one LSTM element: returns c_new, sets hn
__device__ __forceinline__ float cell1(float gi, float gf, float gg, float go, float co, float& hn){
  float si = 1.f / (1.f + expf(-gi));
  float sf = 1.f / (1.f + expf(-gf));
  float so = 1.f / (1.f + expf(-go));
  float cn = sf * co + si * tanhf(gg);
  hn = so * tanhf(cn);
  return cn;
}

// ---- hierarchical grid barrier, FULL ACQ_REL chain (Round-6 strength) ----
// grp counter g at bar[g*64] (g=0..7, 256B apart), root at bar[512], epoch at bar[576].
// HB chain: member release-fence -> ACQ_REL grp RMW -> leader (acquires members)
// -> ACQ_REL root RMW -> root leader (acquires leaders) -> epoch RELEASE
// -> member relaxed spin + ACQUIRE fence.
__device__ __forceinline__ void gbar(int* bar, int target){
  __syncthreads();
  if (threadIdx.x == 0){
    __builtin_amdgcn_fence(__ATOMIC_RELEASE, "agent");   // publish this block's writes
    int* grp   = bar + (blockIdx.x & 7) * 64;
    int* root  = bar + 8 * 64;
    int* epoch = bar + 9 * 64;
    int old = __hip_atomic_fetch_add(grp, 1, __ATOMIC_ACQ_REL, __HIP_MEMORY_SCOPE_AGENT);
    if (old == NBLK / 8 - 1){                            // group leader (last of 32)
      __hip_atomic_store(grp, 0, __ATOMIC_RELAXED, __HIP_MEMORY_SCOPE_AGENT);
      int r = __hip_atomic_fetch_add(root, 1, __ATOMIC_ACQ_REL, __HIP_MEMORY_SCOPE_AGENT);
      if (r == 7){                                       // root leader (last group)
        __hip_atomic_store(root, 0, __ATOMIC_RELAXED, __HIP_MEMORY_SCOPE_AGENT);
        __hip_atomic_store(epoch, target, __ATOMIC_RELEASE, __HIP_MEMORY_SCOPE_AGENT);
      }
    }
    while (__hip_atomic_load(epoch, __ATOMIC_RELAXED, __HIP_MEMORY_SCOPE_AGENT) < target){
      __builtin_amdgcn_s_sleep(2);
    }
    __builtin_amdgcn_fence(__ATOMIC_ACQUIRE, "agent");   // invalidate stale lines
  }
  __syncthreads();
}

// ---- barrier state init (runs every launch/replay) ----
__global__ void k_binit(int* __restrict__ bar){
  for (int i = threadIdx.x; i < 1024; i += 256) bar[i] = 0;
}

// ---- fp32 -> bf16 bulk convert (n4 = element count / 4) ----
__global__ void k_cvt(const float* __restrict__ src, bf16_t* __restrict__ dst, int n4){
  int i = blockIdx.x * 256 + threadIdx.x;
  if (i < n4){
    float4 f = ((const float4*)src)[i];
    ((short4*)dst)[i] = pack4(f);
  }
}

// ---- one-time: gemb[t][b][n] = emb(t,b) . W_ih[:,1024:2048]^T + b_ih[n] + b_hh[n] ----
__global__ __launch_bounds__(256) void k_gemb(const int* __restrict__ caps,
                                              const float* __restrict__ table,
                                              const float* __restrict__ wih,
                                              const float* __restrict__ bih,
                                              const float* __restrict__ bhh,
                                              float* __restrict__ gemb){
  int tid = threadIdx.x;
  int wave = tid >> 6, lane = tid & 63;
  int quad = lane >> 4, r16 = lane & 15;
  int nwb = blockIdx.x * 128 + wave * 32;
  int t = blockIdx.y;                           // one timestep per m-block (m = t*32 + b)
  const float* rowA = table + (size_t)caps[(size_t)r16 * TSTEPS + t] * HID;
  const float* rowB = table + (size_t)caps[(size_t)(r16 + 16) * TSTEPS + t] * HID;
  f32x4 acc[2][2] = {};

  for (int kk = 0; kk < 32; ++kk){
    int ko = kk * 32 + quad * 8;
    s16x8 a0h, a0l, a1h, a1l, b0h, b0l, b1h, b1l;
    load8split(rowA + ko, a0h, a0l);
    load8split(rowB + ko, a1h, a1l);
    load8split(wih + (size_t)(nwb + r16)      * 2048 + 1024 + ko, b0h, b0l);
    load8split(wih + (size_t)(nwb + 16 + r16) * 2048 + 1024 + ko, b1h, b1l);
    acc[0][0] = __builtin_amdgcn_mfma_f32_16x16x32_bf16(a0h, b0h, acc[0][0], 0, 0, 0);
    acc[0][0] = __builtin_amdgcn_mfma_f32_16x16x32_bf16(a0h, b0l, acc[0][0], 0, 0, 0);
    acc[0][0] = __builtin_amdgcn_mfma_f32_16x16x32_bf16(a0l, b0h, acc[0][0], 0, 0, 0);
    acc[1][0] = __builtin_amdgcn_mfma_f32_16x16x32_bf16(a1h, b0h, acc[1][0], 0, 0, 0);
    acc[1][0] = __builtin_amdgcn_mfma_f32_16x16x32_bf16(a1h, b0l, acc[1][0], 0, 0, 0);
    acc[1][0] = __builtin_amdgcn_mfma_f32_16x16x32_bf16(a1l, b0h, acc[1][0], 0, 0, 0);
    acc[0][1] = __builtin_amdgcn_mfma_f32_16x16x32_bf16(a0h, b1h, acc[0][1], 0, 0, 0);
    acc[0][1] = __builtin_amdgcn_mfma_f32_16x16x32_bf16(a0h, b1l, acc[0][1], 0, 0, 0);
    acc[0][1] = __builtin_amdgcn_mfma_f32_16x16x32_bf16(a0l, b1h, acc[0][1], 0, 0, 0);
    acc[1][1] = __builtin_amdgcn_mfma_f32_16x16x32_bf16(a1h, b1h, acc[1][1], 0, 0, 0);
    acc[1][1] = __builtin_amdgcn_mfma_f32_16x16x32_bf16(a1h, b1l, acc[1][1], 0, 0, 0);
    acc[1][1] = __builtin_amdgcn_mfma_f32_16x16x32_bf16(a1l, b1h, acc[1][1], 0, 0, 0);
  }
#pragma unroll
  for (int mt = 0; mt < 2; ++mt)
#pragma unroll
    for (int nt = 0; nt < 2; ++nt)
#pragma unroll
      for (int r = 0; r < 4; ++r){
        int m = mt * 16 + quad * 4 + r;          // b index
        int n = nwb + nt * 16 + r16;
        gemb[((size_t)t * BATCH + m) * NG + n] = acc[mt][nt][r] + bih[n] + bhh[n];
      }
}

// ---- persistent loop kernel: 256 blocks, weights REGISTER-resident ----
__global__ __launch_bounds__(256, 1) void k_loop(const float* __restrict__ feat,
                                                 const float* __restrict__ gemb,
                                                 const float* __restrict__ wih,
                                                 const float* __restrict__ whh,
                                                 float* __restrict__ gbuf,
                                                 bf16_t* __restrict__ hall,
                                                 bf16_t* __restrict__ xh,
                                                 bf16_t* __restrict__ xl,
                                                 int* __restrict__ bar){
  __shared__ float sh[HID];            // h (blocks 0..31 only)
  __shared__ float sw[64];             // softmax weights

  const int bid  = blockIdx.x;
  const int tid  = threadIdx.x;
  const int nwb  = (bid >> 2) * 64;    // n-tile base (64 gate rows)
  const int kc   = bid & 3;            // k-chunk (512 cols)
  const int kb   = kc * 512;

  const int wave = tid >> 6, lane = tid & 63;
  const int quad = lane >> 4, r16 = lane & 15;
  const int wn = wave & 1, wk = wave >> 1;

  // ---- one-time: stage weight fragments into registers (hi/lo split) ----
  s16x8 wb0h[8], wb0l[8], wb1h[8], wb1l[8];
  {
    const int rr0 = nwb + wn * 32 + r16;
    const int rr1 = rr0 + 16;
#pragma unroll
    for (int kk = 0; kk < 8; ++kk){
      int kg = kb + wk * 256 + kk * 32 + quad * 8;
      const float* p0 = (kg < 1024) ? (wih + (size_t)rr0 * 2048 + kg)
                                    : (whh + (size_t)rr0 * 1024 + (kg - 1024));
      const float* p1 = (kg < 1024) ? (wih + (size_t)rr1 * 2048 + kg)
                                    : (whh + (size_t)rr1 * 1024 + (kg - 1024));
      load8split(p0, wb0h[kk], wb0l[kk]);
      load8split(p1, wb1h[kk], wb1l[kk]);
    }
  }

  float4 c_reg = make_float4(0.f, 0.f, 0.f, 0.f);   // blocks 0..31: cell state
  int gen = 0;

  for (int t = 0; t < TSTEPS; ++t){
    // ================= phase A: cell + attention (blocks 0..31) =================
    if (bid < BATCH){
      if (t == 0){
        ((float4*)sh)[tid] = make_float4(0.f, 0.f, 0.f, 0.f);
      } else {
        const float* ge = gemb + ((size_t)(t - 1) * BATCH + bid) * NG;
        float4 gi = ((const float4*)(ge       ))[tid];
        float4 gf = ((const float4*)(ge + 1024))[tid];
        float4 gg = ((const float4*)(ge + 2048))[tid];
        float4 go = ((const float4*)(ge + 3072))[tid];
#pragma unroll
        for (int c = 0; c < KCHUNK; ++c){
          const float* g = gbuf + ((size_t)c * BATCH + bid) * NG;
          float4 a;
          a = ((const float4*)(g       ))[tid]; gi.x+=a.x; gi.y+=a.y; gi.z+=a.z; gi.w+=a.w;
          a = ((const float4*)(g + 1024))[tid]; gf.x+=a.x; gf.y+=a.y; gf.z+=a.z; gf.w+=a.w;
          a = ((const float4*)(g + 2048))[tid]; gg.x+=a.x; gg.y+=a.y; gg.z+=a.z; gg.w+=a.w;
          a = ((const float4*)(g + 3072))[tid]; go.x+=a.x; go.y+=a.y; go.z+=a.z; go.w+=a.w;
        }
        float4 hn, cn;
        cn.x = cell1(gi.x, gf.x, gg.x, go.x, c_reg.x, hn.x);
        cn.y = cell1(gi.y, gf.y, gg.y, go.y, c_reg.y, hn.y);
        cn.z = cell1(gi.z, gf.z, gg.z, go.z, c_reg.z, hn.z);
        cn.w = cell1(gi.w, gf.w, gg.w, go.w, c_reg.w, hn.w);
        c_reg = cn;
        ((float4*)sh)[tid] = hn;
        ((short4*)(hall + ((size_t)(t - 1) * BATCH + bid) * HID))[tid] = pack4(hn);
      }
      __syncthreads();

      const float4* fb4 = (const float4*)(feat + (size_t)bid * LENC * HID);
      const float4* sh4 = (const float4*)sh;
      for (int l = wave; l < LENC; l += 4){
        float acc = 0.f;
        for (int k4 = lane; k4 < 256; k4 += 64){
          float4 f = fb4[l * 256 + k4];
          float4 h = sh4[k4];
          acc = fmaf(f.x, h.x, acc); acc = fmaf(f.y, h.y, acc);
          acc = fmaf(f.z, h.z, acc); acc = fmaf(f.w, h.w, acc);
        }
        acc = warp_sum(acc);
        if (lane == 0) sw[l] = acc;
      }
      __syncthreads();
      if (tid < 64){
        float s = (tid < LENC) ? sw[tid] : -1e30f;
        float m = warp_max(s);
        m = __shfl(m, 0, 64);
        float e = (tid < LENC) ? expf(s - m) : 0.f;
        float ssum = warp_sum(e);
        ssum = __shfl(ssum, 0, 64);
        if (tid < LENC) sw[tid] = e / ssum;
      }
      __syncthreads();
      // context -> x[b][0:1024] (split)
      {
        float4 a = make_float4(0.f, 0.f, 0.f, 0.f);
#pragma unroll 7
        for (int l = 0; l < LENC; ++l){
          float wl = sw[l];
          float4 f = fb4[l * 256 + tid];
          a.x = fmaf(wl, f.x, a.x); a.y = fmaf(wl, f.y, a.y);
          a.z = fmaf(wl, f.z, a.z); a.w = fmaf(wl, f.w, a.w);
        }
        short4 h4, l4;
        split4(a, h4, l4);
        ((short4*)(xh + (size_t)bid * KSTEP))[tid] = h4;
        ((short4*)(xl + (size_t)bid * KSTEP))[tid] = l4;
      }
      // h -> x[b][1024:2048] (split)
      {
        float4 f = ((const float4*)sh)[tid];
        short4 h4, l4;
        split4(f, h4, l4);
        ((short4*)(xh + (size_t)bid * KSTEP + 1024))[tid] = h4;
        ((short4*)(xl + (size_t)bid * KSTEP + 1024))[tid] = l4;
      }
    }
    ++gen; gbar(bar, gen);              // x ready everywhere

    // ================= phase B: gates GEMM, weights in registers =================
    {
      f32x4 acc[2][2] = {};
#pragma unroll
      for (int kk = 0; kk < 8; ++kk){
        int kg = kb + wk * 256 + kk * 32 + quad * 8;
        s16x8 a0h = load8(xh + (size_t)r16        * KSTEP + kg);
        s16x8 a0l = load8(xl + (size_t)r16        * KSTEP + kg);
        s16x8 a1h = load8(xh + (size_t)(r16 + 16) * KSTEP + kg);
        s16x8 a1l = load8(xl + (size_t)(r16 + 16) * KSTEP + kg);
        // hi*hi + hi*lo + lo*hi (lo*lo dropped: 2^-18)
        acc[0][0] = __builtin_amdgcn_mfma_f32_16x16x32_bf16(a0h, wb0h[kk], acc[0][0], 0, 0, 0);
        acc[0][0] = __builtin_amdgcn_mfma_f32_16x16x32_bf16(a0h, wb0l[kk], acc[0][0], 0, 0, 0);
        acc[0][0] = __builtin_amdgcn_mfma_f32_16x16x32_bf16(a0l, wb0h[kk], acc[0][0], 0, 0, 0);
        acc[1][0] = __builtin_amdgcn_mfma_f32_16x16x32_bf16(a1h, wb0h[kk], acc[1][0], 0, 0, 0);
        acc[1][0] = __builtin_amdgcn_mfma_f32_16x16x32_bf16(a1h, wb0l[kk], acc[1][0], 0, 0, 0);
        acc[1][0] = __builtin_amdgcn_mfma_f32_16x16x32_bf16(a1l, wb0h[kk], acc[1][0], 0, 0, 0);
        acc[0][1] = __builtin_amdgcn_mfma_f32_16x16x32_bf16(a0h, wb1h[kk], acc[0][1], 0, 0, 0);
        acc[0][1] = __builtin_amdgcn_mfma_f32_16x16x32_bf16(a0h, wb1l[kk], acc[0][1], 0, 0, 0);
        acc[0][1] = __builtin_amdgcn_mfma_f32_16x16x32_bf16(a0l, wb1h[kk], acc[0][1], 0, 0, 0);
        acc[1][1] = __builtin_amdgcn_mfma_f32_16x16x32_bf16(a1h, wb1h[kk], acc[1][1], 0, 0, 0);
        acc[1][1] = __builtin_amdgcn_mfma_f32_16x16x32_bf16(a1h, wb1l[kk], acc[1][1], 0, 0, 0);
        acc[1][1] = __builtin_amdgcn_mfma_f32_16x16x32_bf16(a1l, wb1h[kk], acc[1][1], 0, 0, 0);
      }
      int kslot = kc * 2 + wk;                   // 0..7
#pragma unroll
      for (int mt = 0; mt < 2; ++mt)
#pragma unroll
        for (int nt = 0; nt < 2; ++nt)
#pragma unroll
          for (int r = 0; r < 4; ++r){
            int m = mt * 16 + quad * 4 + r;      // batch index
            int n = nwb + wn * 32 + nt * 16 + r16;
            gbuf[((size_t)kslot * BATCH + m) * NG + n] = acc[mt][nt][r];
          }
    }
    ++gen; gbar(bar, gen);              // gbuf ready for next step's cell
  }

  // ---- tail: final cell -> hall[TSTEPS-1] ----
  if (bid < BATCH){
    const float* ge = gemb + ((size_t)(TSTEPS - 1) * BATCH + bid) * NG;
    float4 gi = ((const float4*)(ge       ))[tid];
    float4 gf = ((const float4*)(ge + 1024))[tid];
    float4 gg = ((const float4*)(ge + 2048))[tid];
    float4 go = ((const float4*)(ge + 3072))[tid];
#pragma unroll
    for (int c = 0; c < KCHUNK; ++c){
      const float* g = gbuf + ((size_t)c * BATCH + bid) * NG;
      float4 a;
      a = ((const float4*)(g       ))[tid]; gi.x+=a.x; gi.y+=a.y; gi.z+=a.z; gi.w+=a.w;
      a = ((const float4*)(g + 1024))[tid]; gf.x+=a.x; gf.y+=a.y; gf.z+=a.z; gf.w+=a.w;
      a = ((const float4*)(g + 2048))[tid]; gg.x+=a.x; gg.y+=a.y; gg.z+=a.z; gg.w+=a.w;
      a = ((const float4*)(g + 3072))[tid]; go.x+=a.x; go.y+=a.y; go.z+=a.z; go.w+=a.w;
    }
    float4 hn;
    cell1(gi.x, gf.x, gg.x, go.x, c_reg.x, hn.x);
    cell1(gi.y, gf.y, gg.y, go.y, c_reg.y, hn.y);
    cell1(gi.z, gf.z, gg.z, go.z, c_reg.z, hn.z);
    cell1(gi.w, gf.w, gg.w, go.w, c_reg.w, hn.w);
    ((short4*)(hall + ((size_t)(TSTEPS - 1) * BATCH + bid) * HID))[tid] = pack4(hn);
  }
}

// ---- batched logits GEMM (PROVEN flat version, R4/R6): [768x1024]x[1024x32000]^T ----
template <typename WT>
__global__ __launch_bounds__(256) void k_logits(const bf16_t* __restrict__ hall,
                                                const WT* __restrict__ wout,
                                                const float* __restrict__ bout,
                                                float* __restrict__ out){
  int mh = blockIdx.x * 384;
  int n0 = blockIdx.y * 128;
  int tid = threadIdx.x;
  int wave = tid >> 6, lane = tid & 63;
  int wm = wave >> 1, wn = wave & 1;
  int quad = lane >> 4, r16 = lane & 15;

  for (int mc = 0; mc < 3; ++mc){
    int m0 = mh + mc * 128;
    f32x4 acc[4][4] = {};
#pragma unroll 2
    for (int kk = 0; kk < 32; ++kk){
      int k0 = kk * 32 + quad * 8;
      s16x8 af[4], bfr[4];
#pragma unroll
      for (int mt = 0; mt < 4; ++mt){
        int m = m0 + wm * 64 + mt * 16 + r16;
        af[mt] = load8(hall + (size_t)m * HID + k0);
      }
#pragma unroll
      for (int nt = 0; nt < 4; ++nt){
        int n = n0 + wn * 64 + nt * 16 + r16;
        bfr[nt] = load8(wout + (size_t)n * HID + k0);
      }
#pragma unroll
      for (int mt = 0; mt < 4; ++mt)
#pragma unroll
        for (int nt = 0; nt < 4; ++nt)
          acc[mt][nt] = __builtin_amdgcn_mfma_f32_16x16x32_bf16(af[mt], bfr[nt], acc[mt][nt], 0, 0, 0);
    }

#pragma unroll
    for (int mt = 0; mt < 4; ++mt){
      int mbase = m0 + wm * 64 + mt * 16 + quad * 4;
#pragma unroll
      for (int r = 0; r < 4; ++r){
        int m = mbase + r;
        int tt = m >> 5, b = m & 31;            // hall row m = t*32 + b
        size_t outrow = ((size_t)b * TSTEPS + tt) * VOCAB;
#pragma unroll
        for (int nt = 0; nt < 4; ++nt){
          int n = n0 + wn * 64 + nt * 16 + r16;
          out[outrow + n] = acc[mt][nt][r] + bout[n];
        }
      }
    }
  }
}

extern "C" void kernel_launch(void* const* d_in, const int* in_sizes, int n_in,
                              void* d_out, int out_size, void* d_ws, size_t ws_size,
                              hipStream_t stream) {
  const float* feat  = (const float*)d_in[0];
  const int*   caps  = (const int*)d_in[1];
  const float* table = (const float*)d_in[2];
  const float* wih   = (const float*)d_in[3];
  const float* whh   = (const float*)d_in[4];
  const float* bih   = (const float*)d_in[5];
  const float* bhh   = (const float*)d_in[6];
  const float* wout  = (const float*)d_in[7];
  const float* bout  = (const float*)d_in[8];
  float* out = (float*)d_out;
  (void)in_sizes; (void)n_in; (void)out_size;

  char* ws = (char*)d_ws;
  bf16_t* hall  = (bf16_t*)(ws);                 //  1,572,864 ->  1,572,864
  bf16_t* xh    = (bf16_t*)(ws + 1572864);       //    131,072 ->  1,703,936
  bf16_t* xl    = (bf16_t*)(ws + 1703936);       //    131,072 ->  1,835,008
  float*  gbuf  = (float*)(ws + 1835008);        //  4,194,304 ->  6,029,312  (8 split-K partials)
  float*  gemb  = (float*)(ws + 6029312);        // 12,582,912 -> 18,612,224  (emb gates + biases)
  int*    bar   = (int*)  (ws + 18612224);       //      4,096 -> 18,616,320  (hierarchical barrier)
  bf16_t* woutb = (bf16_t*)(ws + 18616320);      // 65,536,000 -> 84,152,320

  const bool useWout = (ws_size >= (size_t)84152320);

  k_binit<<<dim3(1), dim3(256), 0, stream>>>(bar);
  // one-time: embedding contribution to gates for all timesteps (+ biases folded in)
  k_gemb<<<dim3(32, TSTEPS), dim3(256), 0, stream>>>(caps, table, wih, bih, bhh, gemb);
  // persistent 24-step loop (weights register-resident; 2 grid barriers/step)
  k_loop<<<dim3(NBLK), dim3(256), 0, stream>>>(feat, gemb, wih, whh, gbuf, hall, xh, xl, bar);

  if (useWout){
    k_cvt<<<dim3(32000), dim3(256), 0, stream>>>(wout, woutb, VOCAB * HID / 4);
    k_logits<bf16_t><<<dim3(2, VOCAB / 128), dim3(256), 0, stream>>>(hall, woutb, bout, out);
  } else {
    k_logits<float><<<dim3(2, VOCAB / 128), dim3(256), 0, stream>>>(hall, wout, bout, out);
  }
}